// Round 3
// baseline (675.103 us; speedup 1.0000x reference)
//
#include <hip/hip_runtime.h>
#include <stdint.h>

#define NB 2
#define NT 4096
#define NC 768
#define NH 12
#define ND 64
#define NBT (NB*NT)      // 8192
#define NQKV (3*NC)      // 2304

typedef _Float16 half_t;
typedef __attribute__((ext_vector_type(8))) _Float16 f16x8;
typedef __attribute__((ext_vector_type(4))) _Float16 f16x4;
typedef __attribute__((ext_vector_type(2))) __fp16 fp16x2;   // native type of cvt_pkrtz
typedef __attribute__((ext_vector_type(4))) float f32x4;

#define MFMA16(a,b,c) __builtin_amdgcn_mfma_f32_16x16x32_f16((a),(b),(c),0,0,0)

__device__ __forceinline__ void load_lds16(const void* g, void* l) {
    auto gp = reinterpret_cast<__attribute__((address_space(1))) char*>(reinterpret_cast<uintptr_t>(g));
    auto lp = reinterpret_cast<__attribute__((address_space(3))) char*>(reinterpret_cast<uintptr_t>(l));
    __builtin_amdgcn_global_load_lds(gp, lp, 16, 0, 0);
}

// ---------------- pack fp32 -> f16 (vectorized) ----------------
__global__ __launch_bounds__(256) void k_pack(const float* __restrict__ in, half_t* __restrict__ out, int n4) {
    int i = blockIdx.x * 256 + threadIdx.x;
    if (i >= n4) return;
    float4 f = reinterpret_cast<const float4*>(in)[i];
    f16x4 h;
    h[0] = (half_t)f.x; h[1] = (half_t)f.y; h[2] = (half_t)f.z; h[3] = (half_t)f.w;
    reinterpret_cast<f16x4*>(out)[i] = h;
}

// ---------------- pack + transpose: in[K][N] fp32 -> out[N][K] f16 ----------------
__global__ __launch_bounds__(256) void k_packT(const float* __restrict__ in, half_t* __restrict__ out, int N, int K) {
    int idx = blockIdx.x * 256 + threadIdx.x;
    if (idx >= N * K) return;
    int n = idx / K, k = idx - n * K;
    out[idx] = (half_t)in[(size_t)k * N + n];
}

// ---------------- GEMM: C[M][N] = A[M][K=768] * Bt[N][K=768]^T + bias ----------------
template<int OUTF32>
__global__ __launch_bounds__(256) void k_gemm(const half_t* __restrict__ A, const half_t* __restrict__ Bt,
                                              const float* __restrict__ bias, void* __restrict__ out, int N) {
    __shared__ half_t As[128 * 32];
    __shared__ half_t Bs[128 * 32];
    const int tid = threadIdx.x;
    const int lane = tid & 63, w = tid >> 6;
    const int m0 = blockIdx.x * 128, n0 = blockIdx.y * 128;
    const int wm = (w >> 1) * 64, wn = (w & 1) * 64;
    const int lr = lane & 15, lk = (lane >> 4) * 8;

    f32x4 acc[4][4];
#pragma unroll
    for (int a = 0; a < 4; ++a)
#pragma unroll
        for (int bq = 0; bq < 4; ++bq) acc[a][bq] = (f32x4){0.f, 0.f, 0.f, 0.f};

    const int c0 = tid, c1 = 256 + tid;
    const int ldsbase = (tid & ~63) * 16;   // wave-uniform byte base for global_load_lds

    for (int ks = 0; ks < 24; ++ks) {
        const int k0 = ks * 32;
        __syncthreads();
        load_lds16(A  + (size_t)(m0 + (c0 >> 2)) * NC + k0 + (c0 & 3) * 8, (char*)As + ldsbase);
        load_lds16(Bt + (size_t)(n0 + (c0 >> 2)) * NC + k0 + (c0 & 3) * 8, (char*)Bs + ldsbase);
        load_lds16(A  + (size_t)(m0 + (c1 >> 2)) * NC + k0 + (c1 & 3) * 8, (char*)As + 4096 + ldsbase);
        load_lds16(Bt + (size_t)(n0 + (c1 >> 2)) * NC + k0 + (c1 & 3) * 8, (char*)Bs + 4096 + ldsbase);
        __syncthreads();
        f16x8 af[4], bf[4];
#pragma unroll
        for (int mi = 0; mi < 4; ++mi)
            af[mi] = *reinterpret_cast<const f16x8*>(&As[(wm + mi * 16 + lr) * 32 + lk]);
#pragma unroll
        for (int ni = 0; ni < 4; ++ni)
            bf[ni] = *reinterpret_cast<const f16x8*>(&Bs[(wn + ni * 16 + lr) * 32 + lk]);
#pragma unroll
        for (int mi = 0; mi < 4; ++mi)
#pragma unroll
            for (int ni = 0; ni < 4; ++ni)
                acc[mi][ni] = MFMA16(af[mi], bf[ni], acc[mi][ni]);
    }

    const int rg = (lane >> 4) * 4;   // C/D layout: row=(lane>>4)*4+i, col=lane&15
#pragma unroll
    for (int ni = 0; ni < 4; ++ni) {
        const int gn = n0 + wn + ni * 16 + lr;
        const float bv = bias[gn];
#pragma unroll
        for (int mi = 0; mi < 4; ++mi)
#pragma unroll
            for (int i = 0; i < 4; ++i) {
                const size_t gm = (size_t)(m0 + wm + mi * 16 + rg + i);
                const float v = acc[mi][ni][i] + bv;
                if (OUTF32) reinterpret_cast<float*>(out)[gm * N + gn] = v;
                else        reinterpret_cast<half_t*>(out)[gm * N + gn] = (half_t)v;
            }
    }
}

// ---------------- V repack: qkv[.,1536+h*64+d] -> Vt[bh][d][t] (LDS tile transpose) ----------------
__global__ __launch_bounds__(256) void k_vt(const half_t* __restrict__ qkv, half_t* __restrict__ Vt) {
    __shared__ half_t tile[64][72];
    const int tid = threadIdx.x;
    const int t0 = blockIdx.x * 64, bh = blockIdx.y;
    const int b = bh / NH, h = bh - b * NH;
    {
        const int tl = tid >> 2, dc = (tid & 3) * 16;
        const half_t* src = qkv + (size_t)(b * NT + t0 + tl) * NQKV + 2 * NC + h * ND + dc;
        f16x8 v0 = *reinterpret_cast<const f16x8*>(src);
        f16x8 v1 = *reinterpret_cast<const f16x8*>(src + 8);
        *reinterpret_cast<f16x8*>(&tile[tl][dc]) = v0;
        *reinterpret_cast<f16x8*>(&tile[tl][dc + 8]) = v1;
    }
    __syncthreads();
    {
        const int d = tid >> 2, tc = (tid & 3) * 16;
        half_t* dst = Vt + ((size_t)bh * ND + d) * NT + t0 + tc;
        f16x8 o0, o1;
#pragma unroll
        for (int j = 0; j < 8; ++j) o0[j] = tile[tc + j][d];
#pragma unroll
        for (int j = 0; j < 8; ++j) o1[j] = tile[tc + 8 + j][d];
        *reinterpret_cast<f16x8*>(dst) = o0;
        *reinterpret_cast<f16x8*>(dst + 8) = o1;
    }
}

// ---------------- Flash attention v7: score-lookahead pipeline (T15) ----------------
// R1 post-mortem: counted-vmcnt barrier was NEUTRAL (133us) and R0's 2x occupancy
// REGRESSED -> limiter is within-wave serialization: QKT(t) -> (MFMA latency) -> exp2(t)
// -> (VALU chain) -> PV(t), with barrier-locked waves hitting the same pipe in phase.
// Fix: compute QKT(t+1) BEFORE softmax(t)/PV(t). softmax consumes iteration-old scores
// (no MFMA-latency stall); QKT(t+1) MFMAs overlap softmax(t) VALU within the wave.
// Two named score buffers sA/sB, manual unroll-by-2 (static indexing, rule #20).
// Triple buffer; K read 1 tile ahead => barrier waits vmcnt(2) (stage order K,K,V,V:
// the 2 outstanding are the freshest V pair; per-wave vmcnt + s_barrier = block-wide).
// Live-buffer check at iter t: V[t]=buf[t%3], K[t+1]=buf[(t+1)%3], stage t+2 into
// buf[(t+2)%3] whose last read (V[t-1]) was fenced by the iter t-1 barrier.
#define QKT_BLK(SN)                                                              \
    {                                                                            \
        const half_t* Kc = &Kb[kb][0];                                           \
        _Pragma("unroll")                                                        \
        for (int st = 0; st < 4; ++st) {                                         \
            SN[0][st] = (f32x4){0.f, 0.f, 0.f, 0.f};                             \
            SN[1][st] = (f32x4){0.f, 0.f, 0.f, 0.f};                             \
        }                                                                        \
        __builtin_amdgcn_s_setprio(1);                                           \
        _Pragma("unroll")                                                        \
        for (int st = 0; st < 4; ++st) {                                         \
            f16x8 bk0 = *reinterpret_cast<const f16x8*>(&Kc[(st * 16 + lr) * 64 + cA]); \
            SN[0][st] = MFMA16(bk0, aq[0][0], SN[0][st]);                        \
            SN[1][st] = MFMA16(bk0, aq[1][0], SN[1][st]);                        \
            f16x8 bk1 = *reinterpret_cast<const f16x8*>(&Kc[(st * 16 + lr) * 64 + cB]); \
            SN[0][st] = MFMA16(bk1, aq[0][1], SN[0][st]);                        \
            SN[1][st] = MFMA16(bk1, aq[1][1], SN[1][st]);                        \
        }                                                                        \
        __builtin_amdgcn_s_setprio(0);                                           \
        kb = (kb == 2) ? 0 : kb + 1;                                             \
    }

#define SMAX_PV_BLK(SC)                                                          \
    {                                                                            \
        f16x8 pb[2][2];                                                          \
        _Pragma("unroll")                                                        \
        for (int qf = 0; qf < 2; ++qf) {                                         \
            float ps = 0.f;                                                      \
            _Pragma("unroll")                                                    \
            for (int ks = 0; ks < 2; ++ks) {                                     \
                union { f16x8 v; fp16x2 h[4]; } u;                               \
                _Pragma("unroll")                                                \
                for (int hs = 0; hs < 2; ++hs) {                                 \
                    const int st = 2 * ks + hs;                                  \
                    const float p0 = __builtin_amdgcn_exp2f(SC[qf][st][0]);      \
                    const float p1 = __builtin_amdgcn_exp2f(SC[qf][st][1]);      \
                    const float p2 = __builtin_amdgcn_exp2f(SC[qf][st][2]);      \
                    const float p3 = __builtin_amdgcn_exp2f(SC[qf][st][3]);      \
                    u.h[2 * hs]     = __builtin_amdgcn_cvt_pkrtz(p0, p1);        \
                    u.h[2 * hs + 1] = __builtin_amdgcn_cvt_pkrtz(p2, p3);        \
                    ps += (p0 + p1) + (p2 + p3);                                 \
                }                                                                \
                pb[qf][ks] = u.v;                                                \
            }                                                                    \
            l_[qf] += ps;                                                        \
        }                                                                        \
        const half_t* Vc = &Vb[vb][0];                                           \
        __builtin_amdgcn_s_setprio(1);                                           \
        _Pragma("unroll")                                                        \
        for (int ks = 0; ks < 2; ++ks)                                           \
            _Pragma("unroll")                                                    \
            for (int df = 0; df < 4; ++df) {                                     \
                const half_t* vrow = &Vc[(df * 16 + lr) * 64];                   \
                union { f16x8 v; f16x4 q[2]; } va;                               \
                va.q[0] = *reinterpret_cast<const f16x4*>(vrow + vc[ks][0]);     \
                va.q[1] = *reinterpret_cast<const f16x4*>(vrow + vc[ks][1]);     \
                y[0][df] = MFMA16(va.v, pb[0][ks], y[0][df]);                    \
                y[1][df] = MFMA16(va.v, pb[1][ks], y[1][df]);                    \
            }                                                                    \
        __builtin_amdgcn_s_setprio(0);                                           \
        vb = (vb == 2) ? 0 : vb + 1;                                             \
    }

#define STAGE_ADV()                                                              \
    {                                                                            \
        stagebuf(sb, ksrc, vsrc);                                                \
        ksrc += (size_t)64 * NQKV;                                               \
        vsrc += 64;                                                              \
        sb = (sb == 2) ? 0 : sb + 1;                                             \
    }

#define BARRIER_N(N)                                                             \
    {                                                                            \
        asm volatile("s_waitcnt vmcnt(" #N ")" ::: "memory");                    \
        __builtin_amdgcn_sched_barrier(0);                                       \
        __builtin_amdgcn_s_barrier();                                            \
        __builtin_amdgcn_sched_barrier(0);                                       \
    }

__global__ __launch_bounds__(256, 3) void k_attn(const half_t* __restrict__ qkv, const half_t* __restrict__ Vt,
                                                 half_t* __restrict__ Y) {
    __shared__ half_t Kb[3][64 * 64];   // [key][d=64], chunk-swizzled (chunk ^= row&7)
    __shared__ half_t Vb[3][64 * 64];   // [d][t=64], chunk-swizzled
    const int tid = threadIdx.x, lane = tid & 63, w = tid >> 6;
    const int lr = lane & 15, g = lane >> 4;
    const int qt = blockIdx.x, bh = blockIdx.y;
    const int b = bh / NH, h = bh - b * NH;
    const half_t* Qp = qkv + (size_t)b * NT * NQKV + h * ND;        // q cols
    const half_t* Kp = Qp + NC;                                     // k cols
    const half_t* Vbase = Vt + (size_t)bh * ND * NT;                // V^T [d][t]
    const int q0 = qt * 128 + w * 32;

    // staging geometry: 256 threads x 16B = 4KB per instr = 32 rows of 128B; 2 instrs per 8KB tile
    const int sr = tid >> 3;                                   // row 0..31 (instr0), +32 (instr1)
    const int colh = (((tid & 7) << 3)) ^ ((sr & 7) << 3);     // swizzled source col (halfs)
    const int wub = (tid & ~63) * 16;                          // wave-uniform LDS byte base

    // Q fragments (B-operand: col=lr=q), 2 q-frags x 2 d-halves, pre-scaled by 1/sqrt(D)*log2(e)
    f16x8 aq[2][2];
    const half_t cch = (half_t)(0.125f * 1.4426950408889634f);
#pragma unroll
    for (int qf = 0; qf < 2; ++qf)
#pragma unroll
        for (int dh = 0; dh < 2; ++dh) {
            aq[qf][dh] = *reinterpret_cast<const f16x8*>(&Qp[(size_t)(q0 + qf * 16 + lr) * NQKV + dh * 32 + g * 8]);
#pragma unroll
            for (int j = 0; j < 8; ++j) aq[qf][dh][j] = aq[qf][dh][j] * cch;
        }

    // swizzled K-read columns (b128): row = st*16+lr, chunk ^= (lr&7)
    const int swk = (lr & 7) << 3;
    const int cA = (g * 8) ^ swk;          // d-chunk 0
    const int cB = (32 + g * 8) ^ swk;     // d-chunk 1
    // swizzled V-read columns (b64 pairs): units at keys 32ks+g*4 and +16
    const int psw = lr & 7;
    const int goff = (g & 1) << 2;
    const int vc[2][2] = { { (((g >> 1) + 0) ^ psw) * 8 + goff, (((g >> 1) + 2) ^ psw) * 8 + goff },
                           { (((g >> 1) + 4) ^ psw) * 8 + goff, (((g >> 1) + 6) ^ psw) * 8 + goff } };

    f32x4 y[2][4];
#pragma unroll
    for (int qf = 0; qf < 2; ++qf)
#pragma unroll
        for (int df = 0; df < 4; ++df) y[qf][df] = (f32x4){0.f, 0.f, 0.f, 0.f};
    float l_[2] = {0.f, 0.f};

    auto stagebuf = [&](int buf, const half_t* Ks, const half_t* Vs) {
        char* kdst = (char*)&Kb[buf][0] + wub;
        char* vdst = (char*)&Vb[buf][0] + wub;
        load_lds16(Ks, kdst);                                  // K half 0
        load_lds16(Ks + (size_t)32 * NQKV, kdst + 4096);       // K half 1
        load_lds16(Vs, vdst);                                  // V half 0
        load_lds16(Vs + (size_t)32 * NT, vdst + 4096);         // V half 1
    };

    const half_t* ksrc = Kp + (size_t)sr * NQKV + colh;
    const half_t* vsrc = Vbase + (size_t)sr * NT + colh;
    stagebuf(0, ksrc, vsrc);                                    // tile 0
    stagebuf(1, ksrc + (size_t)64 * NQKV, vsrc + 64);           // tile 1
    ksrc += (size_t)128 * NQKV;
    vsrc += 128;

    // per-wave: own stage(0) slice + own K(1) slice landed; barrier -> block-wide
    BARRIER_N(2)

    f32x4 sA[2][4], sB[2][4];
    int kb = 0, vb = 0, sb = 2;

    QKT_BLK(sA)          // QKT(0): kb 0 -> 1

    // main loop: 62 condition-free iterations (t = 0..61), unrolled by 2
    for (int t2 = 0; t2 < 31; ++t2) {
        // t even: consume sA, fill sB
        STAGE_ADV()
        QKT_BLK(sB)
        SMAX_PV_BLK(sA)
        BARRIER_N(2)
        // t odd: consume sB, fill sA
        STAGE_ADV()
        QKT_BLK(sA)
        SMAX_PV_BLK(sB)
        BARRIER_N(2)
    }
    // t = 62: no stage; QKT(63) -> sB; consume sA; drain all loads for V[63]
    QKT_BLK(sB)
    SMAX_PV_BLK(sA)
    BARRIER_N(0)
    // t = 63: consume sB
    SMAX_PV_BLK(sB)

    // l reduce across the 4 g-groups (keys partitioned by g,st), then store
#pragma unroll
    for (int qf = 0; qf < 2; ++qf) {
        float l = l_[qf];
        l += __shfl_xor(l, 16);
        l += __shfl_xor(l, 32);
        const float rl = 1.f / l;
        half_t* Yp = Y + (size_t)(b * NT + q0 + qf * 16 + lr) * NC + h * ND + g * 4;
#pragma unroll
        for (int df = 0; df < 4; ++df) {
            union { f16x4 v; fp16x2 hh[2]; } o;
            o.hh[0] = __builtin_amdgcn_cvt_pkrtz(y[qf][df][0] * rl, y[qf][df][1] * rl);
            o.hh[1] = __builtin_amdgcn_cvt_pkrtz(y[qf][df][2] * rl, y[qf][df][3] * rl);
            *reinterpret_cast<f16x4*>(Yp + df * 16) = o.v;
        }
    }
}

extern "C" void kernel_launch(void* const* d_in, const int* in_sizes, int n_in,
                              void* d_out, int out_size, void* d_ws, size_t ws_size,
                              hipStream_t stream) {
    const float* x  = (const float*)d_in[0];
    const float* Wa = (const float*)d_in[1];
    const float* ba = (const float*)d_in[2];
    const float* Wp = (const float*)d_in[3];
    const float* bp = (const float*)d_in[4];
    float* out = (float*)d_out;

    char* ws = (char*)d_ws;
    half_t* xh   = (half_t*)ws; ws += (size_t)NBT * NC * 2;
    half_t* Wat  = (half_t*)ws; ws += (size_t)NQKV * NC * 2;
    half_t* Wpt  = (half_t*)ws; ws += (size_t)NC * NC * 2;
    half_t* qkvh = (half_t*)ws; ws += (size_t)NBT * NQKV * 2;
    half_t* vt   = (half_t*)ws; ws += (size_t)NB * NH * ND * NT * 2;
    half_t* yh   = (half_t*)ws; ws += (size_t)NBT * NC * 2;

    k_pack<<<(NBT * NC / 4 + 255) / 256, 256, 0, stream>>>(x, xh, NBT * NC / 4);
    k_packT<<<(NQKV * NC + 255) / 256, 256, 0, stream>>>(Wa, Wat, NQKV, NC);
    k_packT<<<(NC * NC + 255) / 256, 256, 0, stream>>>(Wp, Wpt, NC, NC);
    k_gemm<0><<<dim3(NBT / 128, NQKV / 128), 256, 0, stream>>>(xh, Wat, ba, qkvh, NQKV);
    k_vt<<<dim3(NT / 64, NB * NH), 256, 0, stream>>>(qkvh, vt);
    k_attn<<<dim3(NT / 128, NB * NH), 256, 0, stream>>>(qkvh, vt, yh);
    k_gemm<1><<<dim3(NBT / 128, NC / 128), 256, 0, stream>>>(yh, Wpt, bp, out, NC);
}

// Round 4
// 226.481 us; speedup vs baseline: 2.9808x; 2.9808x over previous
//
#include <hip/hip_runtime.h>
#include <stdint.h>

#define NB 2
#define NT 4096
#define NC 768
#define NH 12
#define ND 64
#define NBT (NB*NT)      // 8192
#define NQKV (3*NC)      // 2304

typedef _Float16 half_t;
typedef __attribute__((ext_vector_type(8))) _Float16 f16x8;
typedef __attribute__((ext_vector_type(4))) _Float16 f16x4;
typedef __attribute__((ext_vector_type(2))) __fp16 fp16x2;   // native type of cvt_pkrtz
typedef __attribute__((ext_vector_type(4))) float f32x4;

#define MFMA16(a,b,c) __builtin_amdgcn_mfma_f32_16x16x32_f16((a),(b),(c),0,0,0)

__device__ __forceinline__ void load_lds16(const void* g, void* l) {
    auto gp = reinterpret_cast<__attribute__((address_space(1))) char*>(reinterpret_cast<uintptr_t>(g));
    auto lp = reinterpret_cast<__attribute__((address_space(3))) char*>(reinterpret_cast<uintptr_t>(l));
    __builtin_amdgcn_global_load_lds(gp, lp, 16, 0, 0);
}

// ---------------- pack fp32 -> f16 (vectorized) ----------------
__global__ __launch_bounds__(256) void k_pack(const float* __restrict__ in, half_t* __restrict__ out, int n4) {
    int i = blockIdx.x * 256 + threadIdx.x;
    if (i >= n4) return;
    float4 f = reinterpret_cast<const float4*>(in)[i];
    f16x4 h;
    h[0] = (half_t)f.x; h[1] = (half_t)f.y; h[2] = (half_t)f.z; h[3] = (half_t)f.w;
    reinterpret_cast<f16x4*>(out)[i] = h;
}

// ---------------- pack + transpose: in[K][N] fp32 -> out[N][K] f16 ----------------
__global__ __launch_bounds__(256) void k_packT(const float* __restrict__ in, half_t* __restrict__ out, int N, int K) {
    int idx = blockIdx.x * 256 + threadIdx.x;
    if (idx >= N * K) return;
    int n = idx / K, k = idx - n * K;
    out[idx] = (half_t)in[(size_t)k * N + n];
}

// ---------------- GEMM: C[M][N] = A[M][K=768] * Bt[N][K=768]^T + bias ----------------
template<int OUTF32>
__global__ __launch_bounds__(256) void k_gemm(const half_t* __restrict__ A, const half_t* __restrict__ Bt,
                                              const float* __restrict__ bias, void* __restrict__ out, int N) {
    __shared__ half_t As[128 * 32];
    __shared__ half_t Bs[128 * 32];
    const int tid = threadIdx.x;
    const int lane = tid & 63, w = tid >> 6;
    const int m0 = blockIdx.x * 128, n0 = blockIdx.y * 128;
    const int wm = (w >> 1) * 64, wn = (w & 1) * 64;
    const int lr = lane & 15, lk = (lane >> 4) * 8;

    f32x4 acc[4][4];
#pragma unroll
    for (int a = 0; a < 4; ++a)
#pragma unroll
        for (int bq = 0; bq < 4; ++bq) acc[a][bq] = (f32x4){0.f, 0.f, 0.f, 0.f};

    const int c0 = tid, c1 = 256 + tid;
    const int ldsbase = (tid & ~63) * 16;   // wave-uniform byte base for global_load_lds

    for (int ks = 0; ks < 24; ++ks) {
        const int k0 = ks * 32;
        __syncthreads();
        load_lds16(A  + (size_t)(m0 + (c0 >> 2)) * NC + k0 + (c0 & 3) * 8, (char*)As + ldsbase);
        load_lds16(Bt + (size_t)(n0 + (c0 >> 2)) * NC + k0 + (c0 & 3) * 8, (char*)Bs + ldsbase);
        load_lds16(A  + (size_t)(m0 + (c1 >> 2)) * NC + k0 + (c1 & 3) * 8, (char*)As + 4096 + ldsbase);
        load_lds16(Bt + (size_t)(n0 + (c1 >> 2)) * NC + k0 + (c1 & 3) * 8, (char*)Bs + 4096 + ldsbase);
        __syncthreads();
        f16x8 af[4], bf[4];
#pragma unroll
        for (int mi = 0; mi < 4; ++mi)
            af[mi] = *reinterpret_cast<const f16x8*>(&As[(wm + mi * 16 + lr) * 32 + lk]);
#pragma unroll
        for (int ni = 0; ni < 4; ++ni)
            bf[ni] = *reinterpret_cast<const f16x8*>(&Bs[(wn + ni * 16 + lr) * 32 + lk]);
#pragma unroll
        for (int mi = 0; mi < 4; ++mi)
#pragma unroll
            for (int ni = 0; ni < 4; ++ni)
                acc[mi][ni] = MFMA16(af[mi], bf[ni], acc[mi][ni]);
    }

    const int rg = (lane >> 4) * 4;   // C/D layout: row=(lane>>4)*4+i, col=lane&15
#pragma unroll
    for (int ni = 0; ni < 4; ++ni) {
        const int gn = n0 + wn + ni * 16 + lr;
        const float bv = bias[gn];
#pragma unroll
        for (int mi = 0; mi < 4; ++mi)
#pragma unroll
            for (int i = 0; i < 4; ++i) {
                const size_t gm = (size_t)(m0 + wm + mi * 16 + rg + i);
                const float v = acc[mi][ni][i] + bv;
                if (OUTF32) reinterpret_cast<float*>(out)[gm * N + gn] = v;
                else        reinterpret_cast<half_t*>(out)[gm * N + gn] = (half_t)v;
            }
    }
}

// ---------------- V repack: qkv[.,1536+h*64+d] -> Vt[bh][d][t] (LDS tile transpose) ----------------
__global__ __launch_bounds__(256) void k_vt(const half_t* __restrict__ qkv, half_t* __restrict__ Vt) {
    __shared__ half_t tile[64][72];
    const int tid = threadIdx.x;
    const int t0 = blockIdx.x * 64, bh = blockIdx.y;
    const int b = bh / NH, h = bh - b * NH;
    {
        const int tl = tid >> 2, dc = (tid & 3) * 16;
        const half_t* src = qkv + (size_t)(b * NT + t0 + tl) * NQKV + 2 * NC + h * ND + dc;
        f16x8 v0 = *reinterpret_cast<const f16x8*>(src);
        f16x8 v1 = *reinterpret_cast<const f16x8*>(src + 8);
        *reinterpret_cast<f16x8*>(&tile[tl][dc]) = v0;
        *reinterpret_cast<f16x8*>(&tile[tl][dc + 8]) = v1;
    }
    __syncthreads();
    {
        const int d = tid >> 2, tc = (tid & 3) * 16;
        half_t* dst = Vt + ((size_t)bh * ND + d) * NT + t0 + tc;
        f16x8 o0, o1;
#pragma unroll
        for (int j = 0; j < 8; ++j) o0[j] = tile[tc + j][d];
#pragma unroll
        for (int j = 0; j < 8; ++j) o1[j] = tile[tc + 8 + j][d];
        *reinterpret_cast<f16x8*>(dst) = o0;
        *reinterpret_cast<f16x8*>(dst + 8) = o1;
    }
}

// ---------------- Flash attention v8: q=64 per wave, 2-wave blocks (LDS-traffic halving) ----------------
// R0/R1/R2 post-mortems: scheduling changes (occupancy 2x, counted vmcnt, score lookahead)
// were all neutral-to-negative. Pipe arithmetic: LDS data pipe ~70% busy (2304 cy reads +
// 768 cy conflicts + 384 cy staging writes per ~4990 cy window) = the binding resource;
// every K/V byte is read once PER WAVE (4 waves x 32q). Fix: q=64 per wave -> each K/V
// fragment feeds 4 MFMAs instead of 2; per-CU LDS read traffic HALVES at identical MFMA
// and VALU demand. Block = 2 waves (128 thr) so the grid stays 768 blocks = 3/CU even.
// VGPR: y64 + s64 + aq32 + pb32 + misc ~ 190 -> launch_bounds(128,2) (cap 256, no spill
// -- R2's spill came from the (256,3) 168-reg cap). 2-buffer + __syncthreads (R1 showed
// counted-vmcnt is neutral at this structure).
__global__ __launch_bounds__(128, 2) void k_attn(const half_t* __restrict__ qkv, const half_t* __restrict__ Vt,
                                                 half_t* __restrict__ Y) {
    __shared__ half_t Kb[2][64 * 64];   // [key][d=64], chunk-swizzled (chunk ^= row&7)
    __shared__ half_t Vb[2][64 * 64];   // [d][t=64], chunk-swizzled
    const int tid = threadIdx.x, lane = tid & 63, w = tid >> 6;
    const int lr = lane & 15, g = lane >> 4;
    const int qt = blockIdx.x, bh = blockIdx.y;
    const int b = bh / NH, h = bh - b * NH;
    const half_t* Qp = qkv + (size_t)b * NT * NQKV + h * ND;        // q cols
    const half_t* Kp = Qp + NC;                                     // k cols
    const half_t* Vbase = Vt + (size_t)bh * ND * NT;                // V^T [d][t]
    const int q0 = qt * 128 + w * 64;

    // staging geometry: 128 threads x 16B = 2KB per instr = 16 rows of 128B; 4 instrs per 8KB tile.
    // wave w covers rows 8w..8w+7 of each 16-row group (wub = w*1024 matches row*128 layout).
    const int sr = tid >> 3;                                   // row 0..15 within 16-row group
    const int colh = ((tid & 7) << 3) ^ ((sr & 7) << 3);       // swizzled source col (halfs)
    const int wub = (tid & ~63) * 16;                          // wave-uniform LDS byte base (0/1024)

    // Q fragments (B-operand: col=lr=q), 4 q-frags x 2 d-halves, pre-scaled by 1/sqrt(D)*log2(e)
    f16x8 aq[4][2];
    const half_t cch = (half_t)(0.125f * 1.4426950408889634f);
#pragma unroll
    for (int qf = 0; qf < 4; ++qf)
#pragma unroll
        for (int dh = 0; dh < 2; ++dh) {
            aq[qf][dh] = *reinterpret_cast<const f16x8*>(&Qp[(size_t)(q0 + qf * 16 + lr) * NQKV + dh * 32 + g * 8]);
#pragma unroll
            for (int j = 0; j < 8; ++j) aq[qf][dh][j] = aq[qf][dh][j] * cch;
        }

    // swizzled K-read columns (b128): row = st*16+lr, chunk ^= (lr&7)
    const int swk = (lr & 7) << 3;
    const int cA = (g * 8) ^ swk;          // d-chunk 0
    const int cB = (32 + g * 8) ^ swk;     // d-chunk 1
    // swizzled V-read columns (b64 pairs): units at keys 32ks+g*4 and +16
    const int psw = lr & 7;
    const int goff = (g & 1) << 2;
    const int vc[2][2] = { { (((g >> 1) + 0) ^ psw) * 8 + goff, (((g >> 1) + 2) ^ psw) * 8 + goff },
                           { (((g >> 1) + 4) ^ psw) * 8 + goff, (((g >> 1) + 6) ^ psw) * 8 + goff } };

    f32x4 y[4][4];
#pragma unroll
    for (int qf = 0; qf < 4; ++qf)
#pragma unroll
        for (int df = 0; df < 4; ++df) y[qf][df] = (f32x4){0.f, 0.f, 0.f, 0.f};
    float l_[4] = {0.f, 0.f, 0.f, 0.f};

    auto stagebuf = [&](int buf, const half_t* Ks, const half_t* Vs) {
        char* kdst = (char*)&Kb[buf][0] + wub;
        char* vdst = (char*)&Vb[buf][0] + wub;
#pragma unroll
        for (int i = 0; i < 4; ++i) {
            load_lds16(Ks + (size_t)(16 * i) * NQKV, kdst + 2048 * i);
            load_lds16(Vs + (size_t)(16 * i) * NT,  vdst + 2048 * i);
        }
    };

    const half_t* ksrc = Kp + (size_t)sr * NQKV + colh;
    const half_t* vsrc = Vbase + (size_t)sr * NT + colh;
    stagebuf(0, ksrc, vsrc);
    ksrc += (size_t)64 * NQKV;
    vsrc += 64;
    __syncthreads();
    int cur = 0;

    for (int t = 0; t < NT / 64; ++t) {
        if (t < NT / 64 - 1) {
            stagebuf(cur ^ 1, ksrc, vsrc);
            ksrc += (size_t)64 * NQKV;
            vsrc += 64;
        }

        // ---- QK^T (swapped): s[qf][st][i] = S[key=st*16+g*4+i][q=q0+qf*16+lr] ----
        f32x4 s[4][4];
#pragma unroll
        for (int qf = 0; qf < 4; ++qf)
#pragma unroll
            for (int st = 0; st < 4; ++st) s[qf][st] = (f32x4){0.f, 0.f, 0.f, 0.f};
        const half_t* Kc = &Kb[cur][0];
        __builtin_amdgcn_s_setprio(1);
#pragma unroll
        for (int st = 0; st < 4; ++st) {
            f16x8 bk0 = *reinterpret_cast<const f16x8*>(&Kc[(st * 16 + lr) * 64 + cA]);
            s[0][st] = MFMA16(bk0, aq[0][0], s[0][st]);
            s[1][st] = MFMA16(bk0, aq[1][0], s[1][st]);
            s[2][st] = MFMA16(bk0, aq[2][0], s[2][st]);
            s[3][st] = MFMA16(bk0, aq[3][0], s[3][st]);
            f16x8 bk1 = *reinterpret_cast<const f16x8*>(&Kc[(st * 16 + lr) * 64 + cB]);
            s[0][st] = MFMA16(bk1, aq[0][1], s[0][st]);
            s[1][st] = MFMA16(bk1, aq[1][1], s[1][st]);
            s[2][st] = MFMA16(bk1, aq[2][1], s[2][st]);
            s[3][st] = MFMA16(bk1, aq[3][1], s[3][st]);
        }
        __builtin_amdgcn_s_setprio(0);

        // ---- no-max softmax + lane-local pack: pb[qf][ks] = packed p[2ks..2ks+1][0..3] ----
        f16x8 pb[4][2];
#pragma unroll
        for (int qf = 0; qf < 4; ++qf) {
            float ps = 0.f;
#pragma unroll
            for (int ks = 0; ks < 2; ++ks) {
                union { f16x8 v; fp16x2 h[4]; } u;
#pragma unroll
                for (int hs = 0; hs < 2; ++hs) {   // hs: which st of this ks-pair
                    const int st = 2 * ks + hs;
                    const float p0 = __builtin_amdgcn_exp2f(s[qf][st][0]);
                    const float p1 = __builtin_amdgcn_exp2f(s[qf][st][1]);
                    const float p2 = __builtin_amdgcn_exp2f(s[qf][st][2]);
                    const float p3 = __builtin_amdgcn_exp2f(s[qf][st][3]);
                    u.h[2 * hs]     = __builtin_amdgcn_cvt_pkrtz(p0, p1);
                    u.h[2 * hs + 1] = __builtin_amdgcn_cvt_pkrtz(p2, p3);
                    ps += (p0 + p1) + (p2 + p3);
                }
                pb[qf][ks] = u.v;
            }
            l_[qf] += ps;
        }

        // ---- PV: A = V^T rows (d=df*16+lr, k-slots per key-permutation), B = pb (register) ----
        const half_t* Vc = &Vb[cur][0];
        __builtin_amdgcn_s_setprio(1);
#pragma unroll
        for (int ks = 0; ks < 2; ++ks)
#pragma unroll
            for (int df = 0; df < 4; ++df) {
                const half_t* vrow = &Vc[(df * 16 + lr) * 64];
                union { f16x8 v; f16x4 q[2]; } va;
                va.q[0] = *reinterpret_cast<const f16x4*>(vrow + vc[ks][0]);
                va.q[1] = *reinterpret_cast<const f16x4*>(vrow + vc[ks][1]);
                y[0][df] = MFMA16(va.v, pb[0][ks], y[0][df]);
                y[1][df] = MFMA16(va.v, pb[1][ks], y[1][df]);
                y[2][df] = MFMA16(va.v, pb[2][ks], y[2][df]);
                y[3][df] = MFMA16(va.v, pb[3][ks], y[3][df]);
            }
        __builtin_amdgcn_s_setprio(0);

        __syncthreads();   // drains stage vmcnt + all waves done reading buf[cur]
        cur ^= 1;
    }

    // l reduce across the 4 g-groups (keys partitioned by g,st), then store
#pragma unroll
    for (int qf = 0; qf < 4; ++qf) {
        float l = l_[qf];
        l += __shfl_xor(l, 16);
        l += __shfl_xor(l, 32);
        const float rl = 1.f / l;
        half_t* Yp = Y + (size_t)(b * NT + q0 + qf * 16 + lr) * NC + h * ND + g * 4;
#pragma unroll
        for (int df = 0; df < 4; ++df) {
            union { f16x4 v; fp16x2 hh[2]; } o;
            o.hh[0] = __builtin_amdgcn_cvt_pkrtz(y[qf][df][0] * rl, y[qf][df][1] * rl);
            o.hh[1] = __builtin_amdgcn_cvt_pkrtz(y[qf][df][2] * rl, y[qf][df][3] * rl);
            *reinterpret_cast<f16x4*>(Yp + df * 16) = o.v;
        }
    }
}

extern "C" void kernel_launch(void* const* d_in, const int* in_sizes, int n_in,
                              void* d_out, int out_size, void* d_ws, size_t ws_size,
                              hipStream_t stream) {
    const float* x  = (const float*)d_in[0];
    const float* Wa = (const float*)d_in[1];
    const float* ba = (const float*)d_in[2];
    const float* Wp = (const float*)d_in[3];
    const float* bp = (const float*)d_in[4];
    float* out = (float*)d_out;

    char* ws = (char*)d_ws;
    half_t* xh   = (half_t*)ws; ws += (size_t)NBT * NC * 2;
    half_t* Wat  = (half_t*)ws; ws += (size_t)NQKV * NC * 2;
    half_t* Wpt  = (half_t*)ws; ws += (size_t)NC * NC * 2;
    half_t* qkvh = (half_t*)ws; ws += (size_t)NBT * NQKV * 2;
    half_t* vt   = (half_t*)ws; ws += (size_t)NB * NH * ND * NT * 2;
    half_t* yh   = (half_t*)ws; ws += (size_t)NBT * NC * 2;

    k_pack<<<(NBT * NC / 4 + 255) / 256, 256, 0, stream>>>(x, xh, NBT * NC / 4);
    k_packT<<<(NQKV * NC + 255) / 256, 256, 0, stream>>>(Wa, Wat, NQKV, NC);
    k_packT<<<(NC * NC + 255) / 256, 256, 0, stream>>>(Wp, Wpt, NC, NC);
    k_gemm<0><<<dim3(NBT / 128, NQKV / 128), 256, 0, stream>>>(xh, Wat, ba, qkvh, NQKV);
    k_vt<<<dim3(NT / 64, NB * NH), 256, 0, stream>>>(qkvh, vt);
    k_attn<<<dim3(NT / 128, NB * NH), 128, 0, stream>>>(qkvh, vt, yh);
    k_gemm<1><<<dim3(NBT / 128, NC / 128), 256, 0, stream>>>(yh, Wpt, bp, out, NC);
}

// Round 5
// 205.980 us; speedup vs baseline: 3.2775x; 1.0995x over previous
//
#include <hip/hip_runtime.h>
#include <stdint.h>

#define NB 2
#define NT 4096
#define NC 768
#define NH 12
#define ND 64
#define NBT (NB*NT)      // 8192
#define NQKV (3*NC)      // 2304

typedef _Float16 half_t;
typedef __attribute__((ext_vector_type(8))) _Float16 f16x8;
typedef __attribute__((ext_vector_type(4))) _Float16 f16x4;
typedef __attribute__((ext_vector_type(2))) __fp16 fp16x2;   // native type of cvt_pkrtz
typedef __attribute__((ext_vector_type(4))) float f32x4;

#define MFMA16(a,b,c) __builtin_amdgcn_mfma_f32_16x16x32_f16((a),(b),(c),0,0,0)

__device__ __forceinline__ void load_lds16(const void* g, void* l) {
    auto gp = reinterpret_cast<__attribute__((address_space(1))) char*>(reinterpret_cast<uintptr_t>(g));
    auto lp = reinterpret_cast<__attribute__((address_space(3))) char*>(reinterpret_cast<uintptr_t>(l));
    __builtin_amdgcn_global_load_lds(gp, lp, 16, 0, 0);
}

// ---------------- pack fp32 -> f16 (vectorized) ----------------
__global__ __launch_bounds__(256) void k_pack(const float* __restrict__ in, half_t* __restrict__ out, int n4) {
    int i = blockIdx.x * 256 + threadIdx.x;
    if (i >= n4) return;
    float4 f = reinterpret_cast<const float4*>(in)[i];
    f16x4 h;
    h[0] = (half_t)f.x; h[1] = (half_t)f.y; h[2] = (half_t)f.z; h[3] = (half_t)f.w;
    reinterpret_cast<f16x4*>(out)[i] = h;
}

// ---------------- pack + transpose: in[K][N] fp32 -> out[N][K] f16 ----------------
__global__ __launch_bounds__(256) void k_packT(const float* __restrict__ in, half_t* __restrict__ out, int N, int K) {
    int idx = blockIdx.x * 256 + threadIdx.x;
    if (idx >= N * K) return;
    int n = idx / K, k = idx - n * K;
    out[idx] = (half_t)in[(size_t)k * N + n];
}

// ---------------- GEMM: C[M][N] = A[M][K=768] * Bt[N][K=768]^T + bias ----------------
template<int OUTF32>
__global__ __launch_bounds__(256) void k_gemm(const half_t* __restrict__ A, const half_t* __restrict__ Bt,
                                              const float* __restrict__ bias, void* __restrict__ out, int N) {
    __shared__ half_t As[128 * 32];
    __shared__ half_t Bs[128 * 32];
    const int tid = threadIdx.x;
    const int lane = tid & 63, w = tid >> 6;
    const int m0 = blockIdx.x * 128, n0 = blockIdx.y * 128;
    const int wm = (w >> 1) * 64, wn = (w & 1) * 64;
    const int lr = lane & 15, lk = (lane >> 4) * 8;

    f32x4 acc[4][4];
#pragma unroll
    for (int a = 0; a < 4; ++a)
#pragma unroll
        for (int bq = 0; bq < 4; ++bq) acc[a][bq] = (f32x4){0.f, 0.f, 0.f, 0.f};

    const int c0 = tid, c1 = 256 + tid;
    const int ldsbase = (tid & ~63) * 16;   // wave-uniform byte base for global_load_lds

    for (int ks = 0; ks < 24; ++ks) {
        const int k0 = ks * 32;
        __syncthreads();
        load_lds16(A  + (size_t)(m0 + (c0 >> 2)) * NC + k0 + (c0 & 3) * 8, (char*)As + ldsbase);
        load_lds16(Bt + (size_t)(n0 + (c0 >> 2)) * NC + k0 + (c0 & 3) * 8, (char*)Bs + ldsbase);
        load_lds16(A  + (size_t)(m0 + (c1 >> 2)) * NC + k0 + (c1 & 3) * 8, (char*)As + 4096 + ldsbase);
        load_lds16(Bt + (size_t)(n0 + (c1 >> 2)) * NC + k0 + (c1 & 3) * 8, (char*)Bs + 4096 + ldsbase);
        __syncthreads();
        f16x8 af[4], bf[4];
#pragma unroll
        for (int mi = 0; mi < 4; ++mi)
            af[mi] = *reinterpret_cast<const f16x8*>(&As[(wm + mi * 16 + lr) * 32 + lk]);
#pragma unroll
        for (int ni = 0; ni < 4; ++ni)
            bf[ni] = *reinterpret_cast<const f16x8*>(&Bs[(wn + ni * 16 + lr) * 32 + lk]);
#pragma unroll
        for (int mi = 0; mi < 4; ++mi)
#pragma unroll
            for (int ni = 0; ni < 4; ++ni)
                acc[mi][ni] = MFMA16(af[mi], bf[ni], acc[mi][ni]);
    }

    const int rg = (lane >> 4) * 4;   // C/D layout: row=(lane>>4)*4+i, col=lane&15
#pragma unroll
    for (int ni = 0; ni < 4; ++ni) {
        const int gn = n0 + wn + ni * 16 + lr;
        const float bv = bias[gn];
#pragma unroll
        for (int mi = 0; mi < 4; ++mi)
#pragma unroll
            for (int i = 0; i < 4; ++i) {
                const size_t gm = (size_t)(m0 + wm + mi * 16 + rg + i);
                const float v = acc[mi][ni][i] + bv;
                if (OUTF32) reinterpret_cast<float*>(out)[gm * N + gn] = v;
                else        reinterpret_cast<half_t*>(out)[gm * N + gn] = (half_t)v;
            }
    }
}

// ---------------- V repack: qkv[.,1536+h*64+d] -> Vt[bh][d][t] (LDS tile transpose) ----------------
__global__ __launch_bounds__(256) void k_vt(const half_t* __restrict__ qkv, half_t* __restrict__ Vt) {
    __shared__ half_t tile[64][72];
    const int tid = threadIdx.x;
    const int t0 = blockIdx.x * 64, bh = blockIdx.y;
    const int b = bh / NH, h = bh - b * NH;
    {
        const int tl = tid >> 2, dc = (tid & 3) * 16;
        const half_t* src = qkv + (size_t)(b * NT + t0 + tl) * NQKV + 2 * NC + h * ND + dc;
        f16x8 v0 = *reinterpret_cast<const f16x8*>(src);
        f16x8 v1 = *reinterpret_cast<const f16x8*>(src + 8);
        *reinterpret_cast<f16x8*>(&tile[tl][dc]) = v0;
        *reinterpret_cast<f16x8*>(&tile[tl][dc + 8]) = v1;
    }
    __syncthreads();
    {
        const int d = tid >> 2, tc = (tid & 3) * 16;
        half_t* dst = Vt + ((size_t)bh * ND + d) * NT + t0 + tc;
        f16x8 o0, o1;
#pragma unroll
        for (int j = 0; j < 8; ++j) o0[j] = tile[tc + j][d];
#pragma unroll
        for (int j = 0; j < 8; ++j) o1[j] = tile[tc + 8 + j][d];
        *reinterpret_cast<f16x8*>(dst) = o0;
        *reinterpret_cast<f16x8*>(dst + 8) = o1;
    }
}

// ---------------- Flash attention v9: q=64/wave AND 12 waves/CU (qw x kw wave grid) ----------------
// Round ledger: R0 (8w key-split, 24 waves/CU) regressed: per-wave work halved per barrier.
// R1 (counted vmcnt) neutral. R3 (q=64/wave, 2w blocks, 6 waves/CU): bank conflicts HALVED
// exactly as predicted (1.26e7 -> 6.3e6) but 1.5 waves/SIMD exposed the in-wave dependency
// chain (MfmaUtil 34.7 -> 29). Synthesis: keep v4's 12 waves/CU AND R3's halved LDS traffic.
// Block = 4 waves = 2 q-groups (qw: 64 rows each) x 2 key-halves (kw: 32 keys of the 64-key
// tile; st in {2kw,2kw+1}, PV ks=kw). Per-wave per-iter work = 32 MFMA + 32 exp2 (same as
// v4); per-CU LDS reads halve (each K/V fragment feeds 4 MFMAs). Grid stays 768 = 3/CU.
// Cross-kw y/l reduction once at the end via 34 KB LDS overlay (R0's proven epilogue).
// VGPR peak ~150 < 168 cap of (256,3); spill check = FETCH_SIZE (R2 signature).
struct __align__(16) AttnSmem {
    union {
        struct { half_t K[2][64 * 64]; half_t V[2][64 * 64]; } m;   // 32 KB main
        struct { float y[2][64][64]; float l[2][64][4]; } r;        // 34 KB epilogue
    };
};

__global__ __launch_bounds__(256, 3) void k_attn(const half_t* __restrict__ qkv, const half_t* __restrict__ Vt,
                                                 half_t* __restrict__ Y) {
    __shared__ AttnSmem sm;
    const int tid = threadIdx.x, lane = tid & 63, w = tid >> 6;
    const int qw = w & 1, kw = w >> 1;
    const int lr = lane & 15, g = lane >> 4;
    const int qt = blockIdx.x, bh = blockIdx.y;
    const int b = bh / NH, h = bh - b * NH;
    const half_t* Qp = qkv + (size_t)b * NT * NQKV + h * ND;        // q cols
    const half_t* Kp = Qp + NC;                                     // k cols
    const half_t* Vbase = Vt + (size_t)bh * ND * NT;                // V^T [d][t]
    const int q0 = qt * 128 + qw * 64;

    // staging geometry: 256 threads x 16B = 4KB per instr = 32 rows of 128B; 2 instrs per 8KB tile
    const int sr = tid >> 3;                                   // row 0..31 (instr0), +32 (instr1)
    const int colh = (((tid & 7) << 3)) ^ ((sr & 7) << 3);     // swizzled source col (halfs)
    const int wub = (tid & ~63) * 16;                          // wave-uniform LDS byte base

    // Q fragments (B-operand: col=lr=q), 4 q-frags x 2 d-halves, pre-scaled by 1/sqrt(D)*log2(e)
    f16x8 aq[4][2];
    const half_t cch = (half_t)(0.125f * 1.4426950408889634f);
#pragma unroll
    for (int qf = 0; qf < 4; ++qf)
#pragma unroll
        for (int dh = 0; dh < 2; ++dh) {
            aq[qf][dh] = *reinterpret_cast<const f16x8*>(&Qp[(size_t)(q0 + qf * 16 + lr) * NQKV + dh * 32 + g * 8]);
#pragma unroll
            for (int j = 0; j < 8; ++j) aq[qf][dh][j] = aq[qf][dh][j] * cch;
        }

    // swizzled K-read columns (b128): row = st*16+lr, chunk ^= (lr&7)
    const int swk = (lr & 7) << 3;
    const int cA = (g * 8) ^ swk;          // d-chunk 0
    const int cB = (32 + g * 8) ^ swk;     // d-chunk 1
    // swizzled V-read columns (b64 pairs) for this wave's key-half (ks = kw)
    const int psw = lr & 7;
    const int goff = (g & 1) << 2;
    const int vcol[2] = { (((g >> 1) + 4 * kw + 0) ^ psw) * 8 + goff,
                          (((g >> 1) + 4 * kw + 2) ^ psw) * 8 + goff };

    f32x4 y[4][4];
#pragma unroll
    for (int qf = 0; qf < 4; ++qf)
#pragma unroll
        for (int df = 0; df < 4; ++df) y[qf][df] = (f32x4){0.f, 0.f, 0.f, 0.f};
    float l_[4] = {0.f, 0.f, 0.f, 0.f};

    auto stagebuf = [&](int buf, const half_t* Ks, const half_t* Vs) {
        char* kdst = (char*)&sm.m.K[buf][0] + wub;
        char* vdst = (char*)&sm.m.V[buf][0] + wub;
        load_lds16(Ks, kdst);
        load_lds16(Ks + (size_t)32 * NQKV, kdst + 4096);
        load_lds16(Vs, vdst);
        load_lds16(Vs + (size_t)32 * NT, vdst + 4096);
    };

    const half_t* ksrc = Kp + (size_t)sr * NQKV + colh;
    const half_t* vsrc = Vbase + (size_t)sr * NT + colh;
    stagebuf(0, ksrc, vsrc);
    ksrc += (size_t)64 * NQKV;
    vsrc += 64;
    __syncthreads();
    int cur = 0;
    const int stb = 2 * kw;

    for (int t = 0; t < NT / 64; ++t) {
        if (t < NT / 64 - 1) {
            stagebuf(cur ^ 1, ksrc, vsrc);
            ksrc += (size_t)64 * NQKV;
            vsrc += 64;
        }

        // ---- QK^T (swapped), this wave's 32-key half: s[qf][sl][i], st = stb+sl ----
        f32x4 s[4][2];
#pragma unroll
        for (int qf = 0; qf < 4; ++qf) { s[qf][0] = (f32x4){0.f,0.f,0.f,0.f}; s[qf][1] = (f32x4){0.f,0.f,0.f,0.f}; }
        const half_t* Kc = &sm.m.K[cur][0];
        __builtin_amdgcn_s_setprio(1);
#pragma unroll
        for (int sl = 0; sl < 2; ++sl) {
            const int row = (stb + sl) * 16 + lr;
            f16x8 bk0 = *reinterpret_cast<const f16x8*>(&Kc[row * 64 + cA]);
            s[0][sl] = MFMA16(bk0, aq[0][0], s[0][sl]);
            s[1][sl] = MFMA16(bk0, aq[1][0], s[1][sl]);
            s[2][sl] = MFMA16(bk0, aq[2][0], s[2][sl]);
            s[3][sl] = MFMA16(bk0, aq[3][0], s[3][sl]);
            f16x8 bk1 = *reinterpret_cast<const f16x8*>(&Kc[row * 64 + cB]);
            s[0][sl] = MFMA16(bk1, aq[0][1], s[0][sl]);
            s[1][sl] = MFMA16(bk1, aq[1][1], s[1][sl]);
            s[2][sl] = MFMA16(bk1, aq[2][1], s[2][sl]);
            s[3][sl] = MFMA16(bk1, aq[3][1], s[3][sl]);
        }
        __builtin_amdgcn_s_setprio(0);

        // ---- no-max softmax + lane-local pack: pb[qf] = packed p for this key-half ----
        f16x8 pb[4];
#pragma unroll
        for (int qf = 0; qf < 4; ++qf) {
            float ps = 0.f;
            union { f16x8 v; fp16x2 h[4]; } u;
#pragma unroll
            for (int hs = 0; hs < 2; ++hs) {   // hs: local st within this ks
                const float p0 = __builtin_amdgcn_exp2f(s[qf][hs][0]);
                const float p1 = __builtin_amdgcn_exp2f(s[qf][hs][1]);
                const float p2 = __builtin_amdgcn_exp2f(s[qf][hs][2]);
                const float p3 = __builtin_amdgcn_exp2f(s[qf][hs][3]);
                u.h[2 * hs]     = __builtin_amdgcn_cvt_pkrtz(p0, p1);
                u.h[2 * hs + 1] = __builtin_amdgcn_cvt_pkrtz(p2, p3);
                ps += (p0 + p1) + (p2 + p3);
            }
            pb[qf] = u.v;
            l_[qf] += ps;
        }

        // ---- PV (ks = kw): A = V^T rows, B = pb (register) ----
        const half_t* Vc = &sm.m.V[cur][0];
        __builtin_amdgcn_s_setprio(1);
#pragma unroll
        for (int df = 0; df < 4; ++df) {
            const half_t* vrow = &Vc[(df * 16 + lr) * 64];
            union { f16x8 v; f16x4 q[2]; } va;
            va.q[0] = *reinterpret_cast<const f16x4*>(vrow + vcol[0]);
            va.q[1] = *reinterpret_cast<const f16x4*>(vrow + vcol[1]);
            y[0][df] = MFMA16(va.v, pb[0], y[0][df]);
            y[1][df] = MFMA16(va.v, pb[1], y[1][df]);
            y[2][df] = MFMA16(va.v, pb[2], y[2][df]);
            y[3][df] = MFMA16(va.v, pb[3], y[3][df]);
        }
        __builtin_amdgcn_s_setprio(0);

        __syncthreads();   // drains stage vmcnt + all waves done reading buf[cur]
        cur ^= 1;
    }

    // ---- cross-wave (key-half) reduction: kw=1 publishes y/l, kw=0 combines+stores ----
    if (kw == 1) {
#pragma unroll
        for (int qf = 0; qf < 4; ++qf)
#pragma unroll
            for (int df = 0; df < 4; ++df) {
                const int jb = (qf * 16 + df * 4) ^ ((lane & 7) << 2);   // bank swizzle
                *reinterpret_cast<f32x4*>(&sm.r.y[qw][lane][jb]) = y[qf][df];
            }
#pragma unroll
        for (int qf = 0; qf < 4; ++qf) sm.r.l[qw][lane][qf] = l_[qf];
    }
    __syncthreads();
    if (kw == 0) {
#pragma unroll
        for (int qf = 0; qf < 4; ++qf) {
#pragma unroll
            for (int df = 0; df < 4; ++df) {
                const int jb = (qf * 16 + df * 4) ^ ((lane & 7) << 2);
                const f32x4 yp = *reinterpret_cast<const f32x4*>(&sm.r.y[qw][lane][jb]);
                y[qf][df] += yp;
            }
            float l = l_[qf] + sm.r.l[qw][lane][qf];
            l += __shfl_xor(l, 16);
            l += __shfl_xor(l, 32);
            const float rl = 1.f / l;
            half_t* Yp = Y + (size_t)(b * NT + q0 + qf * 16 + lr) * NC + h * ND + g * 4;
#pragma unroll
            for (int df = 0; df < 4; ++df) {
                union { f16x4 v; fp16x2 hh[2]; } o;
                o.hh[0] = __builtin_amdgcn_cvt_pkrtz(y[qf][df][0] * rl, y[qf][df][1] * rl);
                o.hh[1] = __builtin_amdgcn_cvt_pkrtz(y[qf][df][2] * rl, y[qf][df][3] * rl);
                *reinterpret_cast<f16x4*>(Yp + df * 16) = o.v;
            }
        }
    }
}

extern "C" void kernel_launch(void* const* d_in, const int* in_sizes, int n_in,
                              void* d_out, int out_size, void* d_ws, size_t ws_size,
                              hipStream_t stream) {
    const float* x  = (const float*)d_in[0];
    const float* Wa = (const float*)d_in[1];
    const float* ba = (const float*)d_in[2];
    const float* Wp = (const float*)d_in[3];
    const float* bp = (const float*)d_in[4];
    float* out = (float*)d_out;

    char* ws = (char*)d_ws;
    half_t* xh   = (half_t*)ws; ws += (size_t)NBT * NC * 2;
    half_t* Wat  = (half_t*)ws; ws += (size_t)NQKV * NC * 2;
    half_t* Wpt  = (half_t*)ws; ws += (size_t)NC * NC * 2;
    half_t* qkvh = (half_t*)ws; ws += (size_t)NBT * NQKV * 2;
    half_t* vt   = (half_t*)ws; ws += (size_t)NB * NH * ND * NT * 2;
    half_t* yh   = (half_t*)ws; ws += (size_t)NBT * NC * 2;

    k_pack<<<(NBT * NC / 4 + 255) / 256, 256, 0, stream>>>(x, xh, NBT * NC / 4);
    k_packT<<<(NQKV * NC + 255) / 256, 256, 0, stream>>>(Wa, Wat, NQKV, NC);
    k_packT<<<(NC * NC + 255) / 256, 256, 0, stream>>>(Wp, Wpt, NC, NC);
    k_gemm<0><<<dim3(NBT / 128, NQKV / 128), 256, 0, stream>>>(xh, Wat, ba, qkvh, NQKV);
    k_vt<<<dim3(NT / 64, NB * NH), 256, 0, stream>>>(qkvh, vt);
    k_attn<<<dim3(NT / 128, NB * NH), 256, 0, stream>>>(qkvh, vt, yh);
    k_gemm<1><<<dim3(NBT / 128, NC / 128), 256, 0, stream>>>(yh, Wpt, bp, out, NC);
}